// Round 18
// baseline (14.399 us; speedup 1.0000x reference)
//
#include <hip/hip_runtime.h>

// EctLayer: ect[b,r,t] = sum_{n: batch[n]==b} sigmoid(SCALE*(lin[r] - (x[n]·dir[:,t])))
// N=65536, D=3, T=64, R=64, B=64. SCALE=500.
//
// Round-18: r17 with ONE change: 2048 blocks x 256 threads (TSPLIT=32,
// TQW=2, 4 waves/block) -> 8 independent barrier groups per CU (was 4).
// All serial-phase structure unchanged: single-exposure boundary scan
// (2 int4 + guard per window, +-1024 = 32 sigma), analytic lo(0)/hi(63),
// full-sweep fallback (prob ~0), packed ds_add_u32 histogram, wave-0
// shfl-scan epilogue (uint2/float2).
//  - histogram: u=(nh+R)/step, r0=rint(u), s=sigmoid at r0, si=round(s*2^9):
//    one ds_add_u32 of (1<<20)|si at bin j1=clamp(r0+1,0,64); skip r0>=64.
//    count=high 12 bits (len<2048 -> max 2047*2^20+2^20 < 2^32), si-sum=low 20.
//  - out[r] = countPrefix(bins 0..r) + (bin[r+1] & 0xFFFFF)*2^-9.
//  - disjoint out[b,:,q*2..+2) slices, plain stores; no global atomics,
//    no memset, no pre/post kernels; 3 hot-path syncs.
//  - errors: quant ~0.06, dropped tails <= ~0.2; threshold 19.44.

#define T_DIRS   64
#define R_STEPS  64
#define NROWS    65                     // bins 0..64
#define N_BATCH  64
#define TSPLIT   32
#define TQW      2                      // dirs per block
#define PSW      32                     // point slots per wave
#define THREADS  256
#define NWAVES   4

#define RADIUS_F 1.1f
#define STEP_F   (2.0f * RADIUS_F / (R_STEPS - 1))          // 0.0349206
#define INV_STEP (1.0f / STEP_F)
#define OFF_F    (RADIUS_F * INV_STEP)                      // 31.5
#define MEXP     (-500.0f * STEP_F * 1.4426950408889634f)   // -K*log2(e)
#define FIXP     512.0f
#define INV_FIXP (1.0f / 512.0f)
#define CNT_ONE  (1u << 20)
#define SI_MASK  0xFFFFFu

__global__ __launch_bounds__(THREADS) void ect_kernel(
    const float* __restrict__ x,      // [N,3]
    const float* __restrict__ dirs,   // [3,T]
    const int*   __restrict__ batch,  // [N] sorted, values in [0,64)
    float* __restrict__ out,          // [B,R,T]
    int N)
{
    __shared__ unsigned s_a[NROWS * TQW];       // 520 B packed bins
    __shared__ int      s_lo, s_hi;

    const int tid  = threadIdx.x;
    const int b    = blockIdx.x >> 5;
    const int q    = blockIdx.x & (TSPLIT - 1);
    const int lane = tid & 63;
    const int w    = tid >> 6;
    const int ps   = lane >> 1;                 // point slot 0..31
    const int tq   = lane & (TQW - 1);          // local dir 0..1
    const int tg   = q * TQW + tq;              // global dir

    for (int i = tid; i < NROWS * TQW; i += THREADS) s_a[i] = 0u;
    if (tid == 0) {
        s_lo = (b == 0) ? 0 : -1;               // analytic: batch[j] >= 0
        s_hi = (b == N_BATCH - 1) ? N : -1;     // analytic: batch[j] <= 63
    }

    const float d0 = dirs[tg];
    const float d1 = dirs[T_DIRS + tg];
    const float d2 = dirs[2 * T_DIRS + tg];
    __syncthreads();

    // single-exposure boundary scan: 8 candidates per window per thread.
    // window = [c-1024, c+1024) (32 sigma); all loads issued back-to-back.
    {
        const int seg = N >> 6;                 // 1024
        const int clo = b * seg;
        const int chi = (b + 1) * seg;
        const bool doLo = (b != 0);
        const bool doHi = (b != N_BATCH - 1);   // uniform branches
        const int lob = clo - 1024 + 8 * tid;   // aligned (lob % 4 == 0)
        const int hib = chi - 1024 + 8 * tid;
        // bounds: doLo => b>=1 => lob in [0, 65528]; doHi => b<=62 => same.
        int4 la, lb, ha, hb;
        int  plo = -1, phi = -1;
        if (doLo) {
            la  = *(const int4*)&batch[lob];
            lb  = *(const int4*)&batch[lob + 4];
            plo = (lob == 0) ? -1 : batch[lob - 1];
        }
        if (doHi) {
            ha  = *(const int4*)&batch[hib];
            hb  = *(const int4*)&batch[hib + 4];
            phi = (hib == 0) ? -1 : batch[hib - 1];
        }
        if (doLo) {
            int v[9] = {plo, la.x, la.y, la.z, la.w, lb.x, lb.y, lb.z, lb.w};
#pragma unroll
            for (int i = 0; i < 8; ++i)
                if (v[i + 1] >= b && v[i] < b) s_lo = lob + i;
        }
        if (doHi) {
            int v[9] = {phi, ha.x, ha.y, ha.z, ha.w, hb.x, hb.y, hb.z, hb.w};
#pragma unroll
            for (int i = 0; i < 8; ++i)
                if (v[i + 1] > b && v[i] <= b) s_hi = hib + i;
        }
    }
    __syncthreads();

    // fallback: full coalesced sweep iff a sentinel survived (prob ~0)
    if (s_lo < 0 || s_hi < 0) {
        for (int j = tid; j < N; j += THREADS) {
            int v  = batch[j];
            int vp = (j == 0) ? -1 : batch[j - 1];
            if (v >= b && vp < b)  s_lo = j;
            if (v >  b && vp <= b) s_hi = j;
        }
        __syncthreads();
    }
    const int lo  = (s_lo < 0) ? N : s_lo;      // still -1: segment empty
    const int hi  = (s_hi < 0) ? N : s_hi;      // still -1: tail reaches N
    const int len = hi - lo;
    const float* xb = x + (size_t)lo * 3;

    // inner loop: direct global x reads (L2-resident, 2-lane-uniform addr)
    for (int p = w * PSW + ps; p < len; p += NWAVES * PSW) {
        float x0 = xb[p * 3 + 0];
        float x1 = xb[p * 3 + 1];
        float x2 = xb[p * 3 + 2];
        float nh  = fmaf(x2, d2, fmaf(x1, d1, x0 * d0));
        float u   = fmaf(nh, INV_STEP, OFF_F);
        float r0f = rintf(u);
        float dd  = r0f - u;                               // [-0.5, 0.5]
        float e   = __builtin_amdgcn_exp2f(dd * MEXP);
        float s   = __builtin_amdgcn_rcpf(1.0f + e);       // sigmoid at r0
        unsigned si = (unsigned)fmaf(s, FIXP, 0.5f);       // [0, 2^9]
        int j1 = (int)r0f + 1;
        if (j1 <= R_STEPS) {                    // skip upper-tail trash
            j1 = max(j1, 0);
            atomicAdd(&s_a[j1 * TQW + tq], CNT_ONE | si);  // one ds_add_u32
        }
    }
    __syncthreads();
    if (w != 0) return;                         // single-wave epilogue

    // lane r handles output row r for the block's 2 dirs.
    uint2 rowv = *(const uint2*)&s_a[lane * TQW];          // ds_read_b64
    uint2 r64  = *(const uint2*)&s_a[R_STEPS * TQW];       // row 64 broadcast

    unsigned c0 = rowv.x >> 20, c1 = rowv.y >> 20;
    unsigned s0 = rowv.x & SI_MASK, s1 = rowv.y & SI_MASK;

    // si of row lane+1 (lane 63 takes row 64 directly)
    unsigned n0 = __shfl_down(s0, 1, 64), n1 = __shfl_down(s1, 1, 64);
    if (lane == 63) { n0 = r64.x & SI_MASK; n1 = r64.y & SI_MASK; }

    // 6-step inclusive scan over lanes (rows 0..63)
#pragma unroll
    for (int d = 1; d < 64; d <<= 1) {
        unsigned u0 = __shfl_up(c0, d, 64), u1 = __shfl_up(c1, d, 64);
        if (lane >= d) { c0 += u0; c1 += u1; }
    }

    float2 o;
    o.x = (float)c0 + (float)n0 * INV_FIXP;
    o.y = (float)c1 + (float)n1 * INV_FIXP;
    *(float2*)&out[((size_t)b << 12) | (lane << 6) | (q * TQW)] = o;
}

extern "C" void kernel_launch(void* const* d_in, const int* in_sizes, int n_in,
                              void* d_out, int out_size, void* d_ws, size_t ws_size,
                              hipStream_t stream) {
    const float* x     = (const float*)d_in[0];
    const float* dirs  = (const float*)d_in[1];
    const int*   batch = (const int*)d_in[3];
    float* out = (float*)d_out;
    const int N = in_sizes[3];

    ect_kernel<<<dim3(N_BATCH * TSPLIT), dim3(THREADS), 0, stream>>>(
        x, dirs, batch, out, N);
}

// Round 19
// 11.709 us; speedup vs baseline: 1.2298x; 1.2298x over previous
//
#include <hip/hip_runtime.h>

// EctLayer: ect[b,r,t] = sum_{n: batch[n]==b} sigmoid(SCALE*(lin[r] - (x[n]·dir[:,t])))
// N=65536, D=3, T=64, R=64, B=64. SCALE=500.
//
// Round-19: r17 base with ONE change — inner mapping lane<->point.
//  r15/r17: wave-iter = 16 points x 4 dirs (lane = pslot x tq), 8 serial
//  load exposures of 16 scattered dwords. Now: wave-iter = 64 CONSECUTIVE
//  points (lane = point), each lane computes its point against all 4 block
//  dirs in registers -> 2 serial exposures of fully-coalesced 3x256B loads,
//  4 independent dir-chains per lane interleave exp/rcp latency.
//  Dirs = 12 block-uniform scalars (s_loads). Deposits: same packed
//  ds_add_u32 (1<<20)|si at s_a[j1*4+j], 4 per point (LDS atomics proven
//  non-critical, r13). Scan/epilogue/grid identical to r17.
//  - single-exposure boundary scan (+-1024), analytic lo(0)=0 / hi(63)=N,
//    full-sweep fallback iff sentinel survives (prob ~1e-15).
//  - out[r] = countPrefix(bins 0..r) + (bin[r+1] & 0xFFFFF)*2^-9.
//  - 1024 blocks = (b = bid>>4, q = bid&15) x 512 threads; disjoint
//    out[b,:,q*4..+4) slices, plain float4 stores; no global atomics,
//    no memset, no pre/post kernels; 3 hot-path syncs.
//  - errors: quant ~0.06, dropped tails <= ~0.2; threshold 19.44.

#define T_DIRS   64
#define R_STEPS  64
#define NROWS    65                     // bins 0..64
#define N_BATCH  64
#define TSPLIT   16
#define TQW      4                      // dirs per block
#define THREADS  512
#define NWAVES   8

#define RADIUS_F 1.1f
#define STEP_F   (2.0f * RADIUS_F / (R_STEPS - 1))          // 0.0349206
#define INV_STEP (1.0f / STEP_F)
#define OFF_F    (RADIUS_F * INV_STEP)                      // 31.5
#define MEXP     (-500.0f * STEP_F * 1.4426950408889634f)   // -K*log2(e)
#define FIXP     512.0f
#define INV_FIXP (1.0f / 512.0f)
#define CNT_ONE  (1u << 20)
#define SI_MASK  0xFFFFFu

__global__ __launch_bounds__(THREADS) void ect_kernel(
    const float* __restrict__ x,      // [N,3]
    const float* __restrict__ dirs,   // [3,T]
    const int*   __restrict__ batch,  // [N] sorted, values in [0,64)
    float* __restrict__ out,          // [B,R,T]
    int N)
{
    __shared__ unsigned s_a[NROWS * TQW];       // 1040 B packed bins
    __shared__ int      s_lo, s_hi;

    const int tid  = threadIdx.x;
    const int b    = blockIdx.x >> 4;
    const int q    = blockIdx.x & (TSPLIT - 1);
    const int lane = tid & 63;
    const int w    = tid >> 6;

    for (int i = tid; i < NROWS * TQW; i += THREADS) s_a[i] = 0u;
    if (tid == 0) {
        s_lo = (b == 0) ? 0 : -1;               // analytic: batch[j] >= 0
        s_hi = (b == N_BATCH - 1) ? N : -1;     // analytic: batch[j] <= 63
    }

    // 12 block-uniform dir components -> scalar regs
    float D0[TQW], D1[TQW], D2[TQW];
#pragma unroll
    for (int j = 0; j < TQW; ++j) {
        D0[j] = dirs[q * TQW + j];
        D1[j] = dirs[T_DIRS + q * TQW + j];
        D2[j] = dirs[2 * T_DIRS + q * TQW + j];
    }
    __syncthreads();

    // single-exposure boundary scan: 4 candidates per window per thread.
    {
        const int seg = N >> 6;                 // 1024
        const int clo = b * seg;
        const int chi = (b + 1) * seg;
        const bool doLo = (b != 0);
        const bool doHi = (b != N_BATCH - 1);   // uniform branches
        const int lob = clo - 1024 + 4 * tid;   // 16B-aligned
        const int hib = chi - 1024 + 4 * tid;
        int4 elo, ehi;
        int  plo = -1, phi = -1;
        if (doLo) {
            elo = *(const int4*)&batch[lob];
            plo = (lob == 0) ? -1 : batch[lob - 1];
        }
        if (doHi) {
            ehi = *(const int4*)&batch[hib];
            phi = (hib == 0) ? -1 : batch[hib - 1];
        }
        if (doLo) {
            int v[5] = {plo, elo.x, elo.y, elo.z, elo.w};
#pragma unroll
            for (int i = 0; i < 4; ++i)
                if (v[i + 1] >= b && v[i] < b) s_lo = lob + i;
        }
        if (doHi) {
            int v[5] = {phi, ehi.x, ehi.y, ehi.z, ehi.w};
#pragma unroll
            for (int i = 0; i < 4; ++i)
                if (v[i + 1] > b && v[i] <= b) s_hi = hib + i;
        }
    }
    __syncthreads();

    // fallback: full coalesced sweep iff a sentinel survived (prob ~1e-15)
    if (s_lo < 0 || s_hi < 0) {
        for (int j = tid; j < N; j += THREADS) {
            int v  = batch[j];
            int vp = (j == 0) ? -1 : batch[j - 1];
            if (v >= b && vp < b)  s_lo = j;
            if (v >  b && vp <= b) s_hi = j;
        }
        __syncthreads();
    }
    const int lo  = (s_lo < 0) ? N : s_lo;
    const int hi  = (s_hi < 0) ? N : s_hi;
    const int len = hi - lo;
    const float* xb = x + (size_t)lo * 3;

    // inner loop: lane = point; 64 consecutive points/wave-iter (coalesced);
    // 4 dirs per lane in registers; ~2 serial iterations for len~1024.
    for (int p0 = w * 64; p0 < len; p0 += NWAVES * 64) {
        int p = p0 + lane;
        if (p < len) {
            float x0 = xb[p * 3 + 0];
            float x1 = xb[p * 3 + 1];
            float x2 = xb[p * 3 + 2];
#pragma unroll
            for (int j = 0; j < TQW; ++j) {
                float nh  = fmaf(x2, D2[j], fmaf(x1, D1[j], x0 * D0[j]));
                float u   = fmaf(nh, INV_STEP, OFF_F);
                float r0f = rintf(u);
                float dd  = r0f - u;                           // [-0.5, 0.5]
                float e   = __builtin_amdgcn_exp2f(dd * MEXP);
                float s   = __builtin_amdgcn_rcpf(1.0f + e);   // sigmoid at r0
                unsigned si = (unsigned)fmaf(s, FIXP, 0.5f);   // [0, 2^9]
                int j1 = (int)r0f + 1;
                if (j1 <= R_STEPS) {            // skip upper-tail trash
                    j1 = max(j1, 0);
                    atomicAdd(&s_a[j1 * TQW + j], CNT_ONE | si);
                }
            }
        }
    }
    __syncthreads();
    if (w != 0) return;                         // single-wave epilogue

    // lane r handles output row r for the block's 4 dirs.
    uint4 rowv = *(const uint4*)&s_a[lane * TQW];          // ds_read_b128
    uint4 r64  = *(const uint4*)&s_a[R_STEPS * TQW];       // row 64 broadcast

    unsigned c0 = rowv.x >> 20, c1 = rowv.y >> 20,
             c2 = rowv.z >> 20, c3 = rowv.w >> 20;
    unsigned s0 = rowv.x & SI_MASK, s1 = rowv.y & SI_MASK,
             s2 = rowv.z & SI_MASK, s3 = rowv.w & SI_MASK;

    unsigned n0 = __shfl_down(s0, 1, 64), n1 = __shfl_down(s1, 1, 64),
             n2 = __shfl_down(s2, 1, 64), n3 = __shfl_down(s3, 1, 64);
    if (lane == 63) {
        n0 = r64.x & SI_MASK; n1 = r64.y & SI_MASK;
        n2 = r64.z & SI_MASK; n3 = r64.w & SI_MASK;
    }

#pragma unroll
    for (int d = 1; d < 64; d <<= 1) {
        unsigned u0 = __shfl_up(c0, d, 64), u1 = __shfl_up(c1, d, 64),
                 u2 = __shfl_up(c2, d, 64), u3 = __shfl_up(c3, d, 64);
        if (lane >= d) { c0 += u0; c1 += u1; c2 += u2; c3 += u3; }
    }

    float4 o;
    o.x = (float)c0 + (float)n0 * INV_FIXP;
    o.y = (float)c1 + (float)n1 * INV_FIXP;
    o.z = (float)c2 + (float)n2 * INV_FIXP;
    o.w = (float)c3 + (float)n3 * INV_FIXP;
    *(float4*)&out[((size_t)b << 12) | (lane << 6) | (q * TQW)] = o;
}

extern "C" void kernel_launch(void* const* d_in, const int* in_sizes, int n_in,
                              void* d_out, int out_size, void* d_ws, size_t ws_size,
                              hipStream_t stream) {
    const float* x     = (const float*)d_in[0];
    const float* dirs  = (const float*)d_in[1];
    const int*   batch = (const int*)d_in[3];
    float* out = (float*)d_out;
    const int N = in_sizes[3];

    ect_kernel<<<dim3(N_BATCH * TSPLIT), dim3(THREADS), 0, stream>>>(
        x, dirs, batch, out, N);
}